// Round 2
// baseline (188.729 us; speedup 1.0000x reference)
//
#include <hip/hip_runtime.h>

// Problem constants
#define BB 64
#define TT 4096
#define CC 51
#define DD 64
#define LN_EPS 1e-5f

// ws layout (floats):
//  [0,     3328)  W_t[d][52]  : W transposed, padded col 51 = 0
//  [3328,  7424)  bias[b][64] : sum_c sm[b][c]*Wm[c][d]
//  [7424, 10752)  nsm[b][52]  : (1 - sensor_mask[b][c]) as float, pad 0
//  [10752,10816)  constOut[d] : LN(sum_c Wm[c][:]) * gamma + beta
#define WS_WT    0
#define WS_BIAS  3328
#define WS_NSM   7424
#define WS_CONST 10752

__global__ void ipmask_setup(const float* __restrict__ W,
                             const float* __restrict__ Wm,
                             const float* __restrict__ gamma,
                             const float* __restrict__ beta,
                             const int* __restrict__ sm,   // bool masks arrive as int32
                             float* __restrict__ ws) {
  const int b = blockIdx.x;   // 64 blocks
  const int d = threadIdx.x;  // 64 threads (1 wave)

  // bias[b][d] = sum_c sm[b][c] * Wm[c][d]
  float s = 0.0f;
  for (int c = 0; c < CC; ++c) {
    if (sm[b * CC + c]) s += Wm[c * DD + d];
  }
  ws[WS_BIAS + b * 64 + d] = s;

  // nsm[b][c] = sensor not-masked as float (pad c=51 -> 0)
  if (d < 52) {
    float v = (d < CC) ? (sm[b * CC + d] ? 0.0f : 1.0f) : 0.0f;
    ws[WS_NSM + b * 52 + d] = v;
  }

  if (b == 0) {
    // W transposed: wt[d*52 + c] = W[c][d], pad c=51 -> 0
    for (int c = 0; c < CC; ++c) ws[WS_WT + d * 52 + c] = W[c * DD + d];
    ws[WS_WT + d * 52 + 51] = 0.0f;

    // constant fully-masked row: f[d] = sum_c Wm[c][d], then LN across d
    float f = 0.0f;
    for (int c = 0; c < CC; ++c) f += Wm[c * DD + d];
    float sum = f, sq = f * f;
    for (int off = 32; off > 0; off >>= 1) {
      sum += __shfl_xor(sum, off, 64);
      sq  += __shfl_xor(sq,  off, 64);
    }
    const float mu  = sum * (1.0f / 64.0f);
    const float var = sq * (1.0f / 64.0f) - mu * mu;
    const float rs  = rsqrtf(var + LN_EPS);
    ws[WS_CONST + d] = (f - mu) * rs * gamma[d] + beta[d];
  }
}

// Main kernel: 512 blocks x 256 threads. 8 blocks per b; each block 512 rows;
// each wave: two 64-row tiles. Lane = row within tile; loop over d.
__global__ __launch_bounds__(256, 2)
void ipmask_main(const float* __restrict__ x,
                 const int* __restrict__ tmask,   // bool mask arrives as int32
                 const float* __restrict__ ws,
                 const float* __restrict__ gamma,
                 const float* __restrict__ beta,
                 float* __restrict__ out) {
  // per-wave: 4224-float x/out region (out tile 64 x 66 padded),
  // + 128 floats (mu,rsig), + 64 floats time-mask
  __shared__ float lds[4 * 4224 + 4 * 128 + 4 * 64];

  const int tid  = threadIdx.x;
  const int wave = tid >> 6;
  const int L    = tid & 63;
  const int m16  = L & 15;
  const int b    = blockIdx.x >> 3;
  const int blkT = (blockIdx.x & 7) * 512;

  float* wlds = lds + wave * 4224;
  float* wln  = lds + 4 * 4224 + wave * 128;
  float* wtm  = lds + 4 * 4224 + 4 * 128 + wave * 64;

  const float* wt      = ws + WS_WT;            // uniform -> s_load
  const float* biasRow = ws + WS_BIAS + b * 64; // uniform -> s_load
  const float* nsmRow  = ws + WS_NSM  + b * 52; // uniform -> s_load

  const float4 co4 = ((const float4*)(ws + WS_CONST))[m16];
  const float4 g4  = ((const float4*)gamma)[m16];
  const float4 b4  = ((const float4*)beta)[m16];

  for (int j = 0; j < 2; ++j) {
    const int tileT = blkT + (j * 4 + wave) * 64;
    const size_t rowBase = (size_t)b * TT + (size_t)tileT; // global row index

    // time mask for my row -> LDS (needed transposed at epilogue)
    wtm[L] = tmask[rowBase + L] ? 1.0f : 0.0f;

    // stage x tile: 64 rows x 51 = 3264 floats = 816 float4, coalesced
    const float4* xg4 = (const float4*)(x + rowBase * CC);
    float4* xl4 = (float4*)wlds;
#pragma unroll
    for (int i = 0; i < 13; ++i) {
      const int f4 = L + i * 64;
      if (f4 < 816) xl4[f4] = xg4[f4];
    }
    __syncthreads();

    // my row -> registers, sensor mask folded in (nsm is SGPR-resident)
    float xv[52];
#pragma unroll
    for (int c = 0; c < CC; ++c) xv[c] = wlds[L * CC + c] * nsmRow[c];
    xv[51] = 0.0f;
    __syncthreads();

    // d-loop: W row via scalar loads (SGPRs), 52 fmacs per d
    float sum = 0.0f, sumsq = 0.0f;
    for (int d = 0; d < 64; ++d) {
      const float4* w4 = (const float4*)(wt + d * 52);
      float a0 = biasRow[d], a1 = 0.0f, a2 = 0.0f, a3 = 0.0f;
#pragma unroll
      for (int i = 0; i < 13; ++i) {
        const float4 w = w4[i];
        a0 = fmaf(w.x, xv[4 * i + 0], a0);
        a1 = fmaf(w.y, xv[4 * i + 1], a1);
        a2 = fmaf(w.z, xv[4 * i + 2], a2);
        a3 = fmaf(w.w, xv[4 * i + 3], a3);
      }
      const float acc = (a0 + a1) + (a2 + a3);
      sum += acc;
      sumsq = fmaf(acc, acc, sumsq);
      wlds[L * 66 + d] = acc;   // stride 66: 2-way bank alias = free
    }

    const float mu   = sum * (1.0f / 64.0f);
    const float var  = fmaf(-mu, mu, sumsq * (1.0f / 64.0f));
    const float rsig = rsqrtf(var + LN_EPS);
    ((float2*)wln)[L] = make_float2(mu, rsig);
    __syncthreads();

    // epilogue: transpose out of LDS, LN-normalize, time-mask select, store
    float4* out4 = (float4*)out + rowBase * 16;
#pragma unroll
    for (int g = 0; g < 16; ++g) {
      const int r = g * 4 + (L >> 4);
      const int baseDw = r * 66 + m16 * 4;        // even -> b64-aligned
      const float2 p0 = ((const float2*)wlds)[(baseDw >> 1)];
      const float2 p1 = ((const float2*)wlds)[(baseDw >> 1) + 1];
      const float2 ms = ((const float2*)wln)[r];
      const float tmr = wtm[r];
      float4 o;
      o.x = fmaf((p0.x - ms.x) * ms.y, g4.x, b4.x);
      o.y = fmaf((p0.y - ms.x) * ms.y, g4.y, b4.y);
      o.z = fmaf((p1.x - ms.x) * ms.y, g4.z, b4.z);
      o.w = fmaf((p1.y - ms.x) * ms.y, g4.w, b4.w);
      if (tmr > 0.5f) o = co4;                    // cndmask x4
      out4[g * 64 + L] = o;
    }
    __syncthreads();
  }
}

extern "C" void kernel_launch(void* const* d_in, const int* in_sizes, int n_in,
                              void* d_out, int out_size, void* d_ws, size_t ws_size,
                              hipStream_t stream) {
  const float* x  = (const float*)d_in[0];
  const float* W  = (const float*)d_in[1];
  const float* Wm = (const float*)d_in[2];
  const float* gamma = (const float*)d_in[3];
  const float* beta  = (const float*)d_in[4];
  const int* tmask = (const int*)d_in[5];
  const int* smask = (const int*)d_in[6];
  float* out = (float*)d_out;
  float* ws  = (float*)d_ws;

  ipmask_setup<<<dim3(BB), dim3(DD), 0, stream>>>(W, Wm, gamma, beta, smask, ws);
  ipmask_main<<<dim3(512), dim3(256), 0, stream>>>(x, tmask, ws, gamma, beta, out);
}

// Round 3
// 179.563 us; speedup vs baseline: 1.0510x; 1.0510x over previous
//
#include <hip/hip_runtime.h>

// Problem constants
#define BB 64
#define TT 4096
#define CC 51
#define DD 64
#define LN_EPS 1e-5f

// DPP control codes
#define DPP_QUAD_PERM_1032 0xB1   // quad_perm:[1,0,3,2]  (xor 1)
#define DPP_QUAD_PERM_2301 0x4E   // quad_perm:[2,3,0,1]  (xor 2)
#define DPP_ROW_HALF_MIRR  0x141  // pairs i <-> (7-i) within 8 (crosses quads)
#define DPP_ROW_MIRROR     0x140  // pairs i <-> (15-i) within 16 (crosses halves)

__device__ __forceinline__ float dpp_add(float v, int ctrl_tag) {
  // returns v + permuted(v); ctrl must be a literal at each call site
  int t;
  switch (ctrl_tag) {
    case 0: t = __builtin_amdgcn_update_dpp(0, __float_as_int(v), DPP_QUAD_PERM_1032, 0xF, 0xF, true); break;
    case 1: t = __builtin_amdgcn_update_dpp(0, __float_as_int(v), DPP_QUAD_PERM_2301, 0xF, 0xF, true); break;
    case 2: t = __builtin_amdgcn_update_dpp(0, __float_as_int(v), DPP_ROW_HALF_MIRR,  0xF, 0xF, true); break;
    default: t = __builtin_amdgcn_update_dpp(0, __float_as_int(v), DPP_ROW_MIRROR,    0xF, 0xF, true); break;
  }
  return v + __int_as_float(t);
}

// all-lane sum over the 64-lane wave: 4 DPP stages (VALU) + 2 shfl stages
__device__ __forceinline__ float wave_allsum(float v) {
  v = dpp_add(v, 0);            // 16-sum after these 4 stages
  v = dpp_add(v, 1);
  v = dpp_add(v, 2);
  v = dpp_add(v, 3);
  v += __shfl_xor(v, 16, 64);
  v += __shfl_xor(v, 32, 64);
  return v;
}

// One kernel. Grid 1024 x 256 threads. 16 blocks per batch b; each wave owns
// 64 consecutive rows of that b. Lane = output dim d. Weights live in VGPRs.
__global__ __launch_bounds__(256, 4)
void ipmask_fused(const float* __restrict__ x,
                  const float* __restrict__ W,
                  const float* __restrict__ Wm,
                  const float* __restrict__ gamma,
                  const float* __restrict__ beta,
                  const int* __restrict__ tmask,
                  const int* __restrict__ smask,
                  float* __restrict__ out) {
  const int L    = threadIdx.x & 63;
  // force wave-uniformity so downstream row pointers scalarize to s_load
  const int wave = __builtin_amdgcn_readfirstlane(threadIdx.x >> 6);
  const int b    = blockIdx.x >> 4;              // 16 blocks per b
  const int t0   = ((blockIdx.x & 15) << 8) + (wave << 6);
  const size_t rowBase = (size_t)b * TT + (size_t)t0;

  const int* smRow = smask + b * CC;             // uniform -> s_load

  // ---- per-wave setup: fold sensor mask into W, build bias & masked-const ----
  float Weff[CC];
  float biasL = 0.0f;   // sum_c sm[c] * Wm[c][L]
  float fL    = 0.0f;   // sum_c Wm[c][L]  (fully-masked row pre-LN)
#pragma unroll
  for (int c = 0; c < CC; ++c) {
    const float wv  = W[c * DD + L];             // coalesced, L2/L3-resident
    const float wmv = Wm[c * DD + L];
    const float ms  = (float)smRow[c];           // 0.0 or 1.0, uniform
    Weff[c] = wv - ms * wv;                      // (1 - sm) * W
    biasL   = fmaf(ms, wmv, biasL);
    fL     += wmv;
  }
  const float gL = gamma[L];
  const float bL = beta[L];

  // constant output row for time-masked rows: LN(fL) * gamma + beta
  float constL;
  {
    const float s1 = wave_allsum(fL);
    const float s2 = wave_allsum(fL * fL);
    const float mu = s1 * (1.0f / 64.0f);
    const float vr = fmaf(-mu, mu, s2 * (1.0f / 64.0f));
    const float rs = rsqrtf(vr + LN_EPS);
    constL = fmaf((fL - mu) * rs, gL, bL);
  }

  // ---- stream 64 rows ----
  for (int r = 0; r < 64; ++r) {
    const size_t row = rowBase + (size_t)r;
    const int tm = tmask[row];                   // uniform -> s_load
    float o;
    if (tm == 0) {
      const float* xr = x + row * (size_t)CC;    // uniform -> batched s_loads
      float acc = biasL;
#pragma unroll
      for (int c = 0; c < CC; ++c) acc = fmaf(xr[c], Weff[c], acc);
      const float s1 = wave_allsum(acc);
      const float s2 = wave_allsum(acc * acc);
      const float mu = s1 * (1.0f / 64.0f);
      const float vr = fmaf(-mu, mu, s2 * (1.0f / 64.0f));
      const float rs = rsqrtf(vr + LN_EPS);
      o = fmaf((acc - mu) * rs, gL, bL);
    } else {
      o = constL;                                // wave-uniform branch, no divergence
    }
    out[row * (size_t)DD + L] = o;               // 256 B coalesced store
  }
}

extern "C" void kernel_launch(void* const* d_in, const int* in_sizes, int n_in,
                              void* d_out, int out_size, void* d_ws, size_t ws_size,
                              hipStream_t stream) {
  const float* x     = (const float*)d_in[0];
  const float* W     = (const float*)d_in[1];
  const float* Wm    = (const float*)d_in[2];
  const float* gamma = (const float*)d_in[3];
  const float* beta  = (const float*)d_in[4];
  const int*   tmask = (const int*)d_in[5];
  const int*   smask = (const int*)d_in[6];
  float* out = (float*)d_out;

  ipmask_fused<<<dim3((BB * TT) / 256), dim3(256), 0, stream>>>(
      x, W, Wm, gamma, beta, tmask, smask, out);
}

// Round 4
// 168.506 us; speedup vs baseline: 1.1200x; 1.0656x over previous
//
#include <hip/hip_runtime.h>

#define BB 64
#define TT 4096
#define CC 51
#define DD 64
#define LN_EPS 1e-5f

typedef __attribute__((ext_vector_type(8))) short short8;
typedef __attribute__((ext_vector_type(4))) float f32x4;

// DPP control codes (verified working in Round 3 kernel)
#define DPP_QP_1032   0xB1   // quad_perm xor1
#define DPP_QP_2301   0x4E   // quad_perm xor2
#define DPP_ROW_HMIRR 0x141  // mirror within 8
#define DPP_ROW_MIRR  0x140  // mirror within 16

__device__ __forceinline__ float dpp_add(float v, int tag) {
  int t;
  switch (tag) {
    case 0: t = __builtin_amdgcn_update_dpp(0, __float_as_int(v), DPP_QP_1032,   0xF, 0xF, true); break;
    case 1: t = __builtin_amdgcn_update_dpp(0, __float_as_int(v), DPP_QP_2301,   0xF, 0xF, true); break;
    case 2: t = __builtin_amdgcn_update_dpp(0, __float_as_int(v), DPP_ROW_HMIRR, 0xF, 0xF, true); break;
    default: t = __builtin_amdgcn_update_dpp(0, __float_as_int(v), DPP_ROW_MIRR, 0xF, 0xF, true); break;
  }
  return v + __int_as_float(t);
}

// sum over each contiguous 16-lane group (matches MFMA C-layout row groups)
__device__ __forceinline__ float allsum16(float v) {
  v = dpp_add(v, 0); v = dpp_add(v, 1); v = dpp_add(v, 2); v = dpp_add(v, 3);
  return v;
}
__device__ __forceinline__ float allsum64(float v) {
  v = allsum16(v);
  v += __shfl_xor(v, 16, 64);
  v += __shfl_xor(v, 32, 64);
  return v;
}

// split fp32 -> packed dword: low short = bf16-trunc(x) [k=2c], high short = bf16(x - hi) [k=2c+1]
__device__ __forceinline__ int pack_hl(float x) {
  const unsigned u = __float_as_uint(x);
  const unsigned h = u >> 16;
  const float hf = __uint_as_float(u & 0xFFFF0000u);
  const float res = x - hf;
  const unsigned l = __float_as_uint(res) >> 16;
  return (int)(h | (l << 16));
}

// LDS dword offsets
#define L_XF   0      // A frags: [MT(8)][ks(4)][lane(64)][4 dw]  = 8192 dw
#define L_BM   8192   // B main:  [ks(4)][nt(4)][lane(64)][4 dw]  = 4096 dw
#define L_BC   12288  // B corr (same shape)                      = 4096 dw
#define L_BIAS 16384  // 64
#define L_CONS 16448  // 64
#define L_TM   16512  // 128
#define L_TOT  16640

// Block = 256 threads (4 waves) = 128 rows of one b. Grid = 64*32 = 2048.
__global__ __launch_bounds__(256, 2)
void ipmask_mfma(const float* __restrict__ x, const float* __restrict__ W,
                 const float* __restrict__ Wm, const float* __restrict__ gamma,
                 const float* __restrict__ beta, const int* __restrict__ tmask,
                 const int* __restrict__ smask, float* __restrict__ out) {
  __shared__ int lds[L_TOT];
  const int t = threadIdx.x, L = t & 63, w = t >> 6;
  const int q = L >> 4, m16 = L & 15;
  const int b = blockIdx.x >> 5, tile = blockIdx.x & 31;
  const int rowBase = (b << 12) + (tile << 7);

  // ---- phase 0: zero the A-frag region (pad K columns must be exactly 0) ----
  {
    const int4 z = make_int4(0, 0, 0, 0);
    int4* p = (int4*)lds;
#pragma unroll
    for (int r = 0; r < 8; ++r) p[t + r * 256] = z;
  }
  __syncthreads();

  // ---- phase 1a: build B frags. thread covers d=L; g = w*4+r -> ks=w, quad=r ----
#pragma unroll
  for (int r = 0; r < 4; ++r) {
    const int g = w * 4 + r;
    int m0, m1, m2, m3, c0, c1, c2, c3;
    int* md[4] = {&m0, &m1, &m2, &m3};
    int* cd[4] = {&c0, &c1, &c2, &c3};
#pragma unroll
    for (int j = 0; j < 4; ++j) {
      const int c = g * 4 + j;
      float we = 0.0f;
      if (c < CC) {
        const float wv = W[c * DD + L];
        we = smask[b * CC + c] ? 0.0f : wv;
      }
      const unsigned u = __float_as_uint(we);
      const unsigned h = u >> 16;
      const float hf = __uint_as_float(u & 0xFFFF0000u);
      const unsigned l = __float_as_uint(we - hf) >> 16;
      *md[j] = (int)(h | (h << 16));  // (wh, wh) -> pairs (xh, xl)
      *cd[j] = (int)l;                // (wl, 0)  -> pairs (xh, --)
    }
    const int fb = ((w * 4 + q) * 64 + r * 16 + m16) * 4;
    *(int4*)(lds + L_BM + fb) = make_int4(m0, m1, m2, m3);
    *(int4*)(lds + L_BC + fb) = make_int4(c0, c1, c2, c3);
  }

  // ---- phase 1b: bias + const row (wave 0), tmask stage ----
  if (w == 0) {
    float bs = 0.0f, f = 0.0f;
    for (int c = 0; c < CC; ++c) {
      const float wmv = Wm[c * DD + L];
      const float sf = (float)smask[b * CC + c];
      bs = fmaf(sf, wmv, bs);
      f += wmv;
    }
    lds[L_BIAS + L] = __float_as_int(bs);
    const float s1 = allsum64(f);
    const float s2 = allsum64(f * f);
    const float mu = s1 * (1.0f / 64.0f);
    const float vr = fmaf(-mu, mu, s2 * (1.0f / 64.0f));
    const float rs = rsqrtf(vr + LN_EPS);
    lds[L_CONS + L] = __float_as_int(fmaf((f - mu) * rs, gamma[L], beta[L]));
  }
  if (t < 128) lds[L_TM + t] = tmask[rowBase + t];

  // ---- phase 1c: stage x as packed (hi|lo) dwords into frag-major layout ----
  // block x chunk = 128 rows * 51 = 6528 floats = 1632 float4 (16B-aligned).
  {
    const float4* xg = (const float4*)(x + (size_t)rowBase * CC);
#pragma unroll
    for (int r2 = 0; r2 < 7; ++r2) {
      const int i = r2 * 256 + t;
      if (i < 1632) {
        const float4 v = xg[i];
        const float vv[4] = {v.x, v.y, v.z, v.w};
        const int e0 = i * 4;
#pragma unroll
        for (int j = 0; j < 4; ++j) {
          const int e = e0 + j;
          const int row = e / CC;
          const int c = e - row * CC;
          const int MT = row >> 4, ks = c >> 4, qa = (c >> 2) & 3, sl = c & 3;
          lds[L_XF + ((MT * 4 + ks) * 64 + qa * 16 + (row & 15)) * 4 + sl] = pack_hl(vv[j]);
        }
      }
    }
  }
  __syncthreads();

  // ---- phase 2: MFMA. wave w owns MT = 2w, 2w+1 ----
  float gvec[4], bvec[4], cons[4];
  f32x4 acc[2][4];
#pragma unroll
  for (int nt = 0; nt < 4; ++nt) {
    const float bias_nt = __int_as_float(lds[L_BIAS + nt * 16 + m16]);
    cons[nt] = __int_as_float(lds[L_CONS + nt * 16 + m16]);
    gvec[nt] = gamma[nt * 16 + m16];
    bvec[nt] = beta[nt * 16 + m16];
#pragma unroll
    for (int m = 0; m < 2; ++m) {
      acc[m][nt][0] = bias_nt; acc[m][nt][1] = bias_nt;
      acc[m][nt][2] = bias_nt; acc[m][nt][3] = bias_nt;
    }
  }

#pragma unroll
  for (int ks = 0; ks < 4; ++ks) {
    short8 bm[4], bc[4];
#pragma unroll
    for (int nt = 0; nt < 4; ++nt) {
      bm[nt] = *(const short8*)(lds + L_BM + ((ks * 4 + nt) * 64 + L) * 4);
      bc[nt] = *(const short8*)(lds + L_BC + ((ks * 4 + nt) * 64 + L) * 4);
    }
#pragma unroll
    for (int m = 0; m < 2; ++m) {
      const int MT = w * 2 + m;
      const short8 a = *(const short8*)(lds + L_XF + ((MT * 4 + ks) * 64 + L) * 4);
#pragma unroll
      for (int nt = 0; nt < 4; ++nt) {
        acc[m][nt] = __builtin_amdgcn_mfma_f32_16x16x32_bf16(a, bm[nt], acc[m][nt], 0, 0, 0);
        acc[m][nt] = __builtin_amdgcn_mfma_f32_16x16x32_bf16(a, bc[nt], acc[m][nt], 0, 0, 0);
      }
    }
  }

  // ---- epilogue: LN per row (16-lane DPP), time-mask select, store ----
#pragma unroll
  for (int m = 0; m < 2; ++m) {
    const int MT = w * 2 + m;
#pragma unroll
    for (int rg = 0; rg < 4; ++rg) {
      float su = 0.0f, sq = 0.0f;
#pragma unroll
      for (int nt = 0; nt < 4; ++nt) {
        const float v = acc[m][nt][rg];
        su += v;
        sq = fmaf(v, v, sq);
      }
      su = allsum16(su);
      sq = allsum16(sq);
      const float mu = su * (1.0f / 64.0f);
      const float vr = fmaf(-mu, mu, sq * (1.0f / 64.0f));
      const float rs = rsqrtf(vr + LN_EPS);
      const int row16 = q * 4 + rg;
      const int tm = lds[L_TM + MT * 16 + row16];
      const size_t obase = ((size_t)(rowBase + MT * 16 + row16)) * DD;
#pragma unroll
      for (int nt = 0; nt < 4; ++nt) {
        float val = fmaf((acc[m][nt][rg] - mu) * rs, gvec[nt], bvec[nt]);
        if (tm) val = cons[nt];
        out[obase + nt * 16 + m16] = val;
      }
    }
  }
}

extern "C" void kernel_launch(void* const* d_in, const int* in_sizes, int n_in,
                              void* d_out, int out_size, void* d_ws, size_t ws_size,
                              hipStream_t stream) {
  const float* x     = (const float*)d_in[0];
  const float* W     = (const float*)d_in[1];
  const float* Wm    = (const float*)d_in[2];
  const float* gamma = (const float*)d_in[3];
  const float* beta  = (const float*)d_in[4];
  const int*   tmask = (const int*)d_in[5];
  const int*   smask = (const int*)d_in[6];
  float* out = (float*)d_out;

  ipmask_mfma<<<dim3(BB * 32), dim3(256), 0, stream>>>(
      x, W, Wm, gamma, beta, tmask, smask, out);
}

// Round 5
// 154.240 us; speedup vs baseline: 1.2236x; 1.0925x over previous
//
#include <hip/hip_runtime.h>

#define BB 64
#define TT 4096
#define CC 51
#define DD 64
#define LN_EPS 1e-5f

typedef __attribute__((ext_vector_type(8))) short short8;
typedef __attribute__((ext_vector_type(4))) float f32x4;

union FragU { int i[4]; short8 s; };

// DPP control codes (verified R3/R4)
#define DPP_QP_1032   0xB1
#define DPP_QP_2301   0x4E
#define DPP_ROW_HMIRR 0x141
#define DPP_ROW_MIRR  0x140

__device__ __forceinline__ float dpp_add(float v, int tag) {
  int t;
  switch (tag) {
    case 0: t = __builtin_amdgcn_update_dpp(0, __float_as_int(v), DPP_QP_1032,   0xF, 0xF, true); break;
    case 1: t = __builtin_amdgcn_update_dpp(0, __float_as_int(v), DPP_QP_2301,   0xF, 0xF, true); break;
    case 2: t = __builtin_amdgcn_update_dpp(0, __float_as_int(v), DPP_ROW_HMIRR, 0xF, 0xF, true); break;
    default: t = __builtin_amdgcn_update_dpp(0, __float_as_int(v), DPP_ROW_MIRR, 0xF, 0xF, true); break;
  }
  return v + __int_as_float(t);
}
__device__ __forceinline__ float allsum16(float v) {
  v = dpp_add(v, 0); v = dpp_add(v, 1); v = dpp_add(v, 2); v = dpp_add(v, 3);
  return v;
}
__device__ __forceinline__ float allsum64(float v) {
  v = allsum16(v);
  v += __shfl_xor(v, 16, 64);
  v += __shfl_xor(v, 32, 64);
  return v;
}

// fp32 -> packed (bf16 hi | bf16 lo) dword; k=2c gets hi (low short), k=2c+1 gets lo
__device__ __forceinline__ int pack_hl(float x) {
  const unsigned u = __float_as_uint(x);
  const unsigned h = u >> 16;
  const float hf = __uint_as_float(u & 0xFFFF0000u);
  const unsigned l = __float_as_uint(x - hf) >> 16;
  return (int)(h | (l << 16));
}

// ---- setup: bias[b][64], constRow[b][64] -> ws (64*128 floats = 32.8 KB) ----
__global__ void ipmask_setup2(const float* __restrict__ Wm,
                              const float* __restrict__ gamma,
                              const float* __restrict__ beta,
                              const int* __restrict__ smask,
                              float* __restrict__ ws) {
  const int b = blockIdx.x, d = threadIdx.x;
  float bs = 0.0f, f = 0.0f;
  for (int c = 0; c < CC; ++c) {
    const float wmv = Wm[c * DD + d];
    const float sf = (float)smask[b * CC + c];
    bs = fmaf(sf, wmv, bs);
    f += wmv;
  }
  ws[b * 128 + d] = bs;
  const float s1 = allsum64(f);
  const float s2 = allsum64(f * f);
  const float mu = s1 * (1.0f / 64.0f);
  const float vr = fmaf(-mu, mu, s2 * (1.0f / 64.0f));
  const float rs = rsqrtf(vr + LN_EPS);
  ws[b * 128 + 64 + d] = fmaf((f - mu) * rs, gamma[d], beta[d]);
}

// ---- main: LDS-free. 1024 blocks x 256 thr; wave = 64 rows (4 M-tiles). ----
__global__ __launch_bounds__(256, 4)
void ipmask_mfma2(const float* __restrict__ x, const float* __restrict__ W,
                  const float* __restrict__ gamma, const float* __restrict__ beta,
                  const int* __restrict__ tmask, const int* __restrict__ smask,
                  const float* __restrict__ ws, float* __restrict__ out) {
  const int t = threadIdx.x, L = t & 63;
  const int q = L >> 4, m16 = L & 15;
  const int gw = (blockIdx.x << 2) + (t >> 6);      // global wave id 0..4095
  const int b = gw >> 6;                            // 64 waves per batch b
  const int rowBase = (b << 12) + ((gw & 63) << 6); // 64 rows per wave

  const int* smB = smask + b * CC;

  // acc init = bias (broadcast along rows)
  f32x4 acc[4][4];
#pragma unroll
  for (int nt = 0; nt < 4; ++nt) {
    const float bias_nt = ws[b * 128 + nt * 16 + m16];
#pragma unroll
    for (int mt = 0; mt < 4; ++mt) {
      acc[mt][nt][0] = bias_nt; acc[mt][nt][1] = bias_nt;
      acc[mt][nt][2] = bias_nt; acc[mt][nt][3] = bias_nt;
    }
  }

#pragma unroll
  for (int ks = 0; ks < 4; ++ks) {
    // ---- build B frags for this ks in registers (W is L2/L3-hot) ----
    FragU bmu[4], bcu[4];
#pragma unroll
    for (int j = 0; j < 4; ++j) {
      const int c = ks * 16 + q * 4 + j;            // q<4 known -> ks<3 needs no guard
      const int smv = (c < CC) ? smB[c] : 1;
#pragma unroll
      for (int nt = 0; nt < 4; ++nt) {
        const int n = nt * 16 + m16;
        float we = 0.0f;
        if (c < CC) we = W[c * DD + n];
        if (smv) we = 0.0f;
        const unsigned u = __float_as_uint(we);
        const unsigned h = u >> 16;
        const float hf = __uint_as_float(u & 0xFFFF0000u);
        const unsigned l = __float_as_uint(we - hf) >> 16;
        bmu[nt].i[j] = (int)(h | (h << 16));        // (wh,wh) pairs (xh,xl)
        bcu[nt].i[j] = (int)l;                      // (wl,0)  pairs (xh,--)
      }
    }

#pragma unroll
    for (int mt = 0; mt < 4; ++mt) {
      const int row = rowBase + mt * 16 + m16;
      const float* xr = x + (size_t)row * CC;
      FragU au;
#pragma unroll
      for (int j = 0; j < 4; ++j) {
        const int c = ks * 16 + q * 4 + j;
        const float xv = (c < CC) ? xr[c] : 0.0f;   // independent dword loads
        au.i[j] = pack_hl(xv);
      }
#pragma unroll
      for (int nt = 0; nt < 4; ++nt) {
        acc[mt][nt] = __builtin_amdgcn_mfma_f32_16x16x32_bf16(au.s, bmu[nt].s, acc[mt][nt], 0, 0, 0);
        acc[mt][nt] = __builtin_amdgcn_mfma_f32_16x16x32_bf16(au.s, bcu[nt].s, acc[mt][nt], 0, 0, 0);
      }
    }
  }

  // ---- epilogue: LN per row (16-lane DPP groups), tmask select, store ----
  float g_[4], b_[4], cons_[4];
#pragma unroll
  for (int nt = 0; nt < 4; ++nt) {
    g_[nt] = gamma[nt * 16 + m16];
    b_[nt] = beta[nt * 16 + m16];
    cons_[nt] = ws[b * 128 + 64 + nt * 16 + m16];
  }
#pragma unroll
  for (int mt = 0; mt < 4; ++mt) {
#pragma unroll
    for (int rg = 0; rg < 4; ++rg) {
      float su = 0.0f, sq = 0.0f;
#pragma unroll
      for (int nt = 0; nt < 4; ++nt) {
        const float v = acc[mt][nt][rg];
        su += v;
        sq = fmaf(v, v, sq);
      }
      su = allsum16(su);
      sq = allsum16(sq);
      const float mu = su * (1.0f / 64.0f);
      const float vr = fmaf(-mu, mu, sq * (1.0f / 64.0f));
      const float rs = rsqrtf(vr + LN_EPS);
      const int row = rowBase + mt * 16 + q * 4 + rg;
      const int tm = tmask[row];
      const size_t obase = (size_t)row * DD;
#pragma unroll
      for (int nt = 0; nt < 4; ++nt) {
        float val = fmaf((acc[mt][nt][rg] - mu) * rs, g_[nt], b_[nt]);
        if (tm) val = cons_[nt];
        out[obase + nt * 16 + m16] = val;
      }
    }
  }
}

extern "C" void kernel_launch(void* const* d_in, const int* in_sizes, int n_in,
                              void* d_out, int out_size, void* d_ws, size_t ws_size,
                              hipStream_t stream) {
  const float* x     = (const float*)d_in[0];
  const float* W     = (const float*)d_in[1];
  const float* Wm    = (const float*)d_in[2];
  const float* gamma = (const float*)d_in[3];
  const float* beta  = (const float*)d_in[4];
  const int*   tmask = (const int*)d_in[5];
  const int*   smask = (const int*)d_in[6];
  float* out = (float*)d_out;
  float* ws  = (float*)d_ws;

  ipmask_setup2<<<dim3(BB), dim3(DD), 0, stream>>>(Wm, gamma, beta, smask, ws);
  ipmask_mfma2<<<dim3(1024), dim3(256), 0, stream>>>(
      x, W, gamma, beta, tmask, smask, ws, out);
}

// Round 6
// 129.304 us; speedup vs baseline: 1.4596x; 1.1929x over previous
//
#include <hip/hip_runtime.h>

#define BB 64
#define TT 4096
#define CC 51
#define DD 64
#define LN_EPS 1e-5f

typedef __attribute__((ext_vector_type(8))) short short8;
typedef __attribute__((ext_vector_type(4))) float f32x4;

union FragU { int i[4]; short8 s; };

// DPP control codes (verified R3-R5)
#define DPP_QP_1032   0xB1
#define DPP_QP_2301   0x4E
#define DPP_ROW_HMIRR 0x141
#define DPP_ROW_MIRR  0x140

__device__ __forceinline__ float dpp_add(float v, int tag) {
  int t;
  switch (tag) {
    case 0: t = __builtin_amdgcn_update_dpp(0, __float_as_int(v), DPP_QP_1032,   0xF, 0xF, true); break;
    case 1: t = __builtin_amdgcn_update_dpp(0, __float_as_int(v), DPP_QP_2301,   0xF, 0xF, true); break;
    case 2: t = __builtin_amdgcn_update_dpp(0, __float_as_int(v), DPP_ROW_HMIRR, 0xF, 0xF, true); break;
    default: t = __builtin_amdgcn_update_dpp(0, __float_as_int(v), DPP_ROW_MIRR, 0xF, 0xF, true); break;
  }
  return v + __int_as_float(t);
}
__device__ __forceinline__ float allsum16(float v) {
  v = dpp_add(v, 0); v = dpp_add(v, 1); v = dpp_add(v, 2); v = dpp_add(v, 3);
  return v;
}
__device__ __forceinline__ float allsum64(float v) {
  v = allsum16(v);
  v += __shfl_xor(v, 16, 64);
  v += __shfl_xor(v, 32, 64);
  return v;
}

// fp32 -> packed (bf16 hi | bf16 lo) dword; k=2c gets hi (low short), 2c+1 lo
__device__ __forceinline__ int pack_hl(float x) {
  const unsigned u = __float_as_uint(x);
  const unsigned h = u >> 16;
  const float hf = __uint_as_float(u & 0xFFFF0000u);
  const unsigned l = __float_as_uint(x - hf) >> 16;
  return (int)(h | (l << 16));
}

// ---- setup: bias[b][64], constRow[b][64] -> ws. grid 64 x 256 (c split) ----
__global__ void ipmask_setup3(const float* __restrict__ Wm,
                              const float* __restrict__ gamma,
                              const float* __restrict__ beta,
                              const int* __restrict__ smask,
                              float* __restrict__ ws) {
  __shared__ float red[8][64];
  const int t = threadIdx.x, L = t & 63, w = t >> 6;
  const int b = blockIdx.x;
  const int c0 = w * 13, c1 = (c0 + 13 < CC) ? c0 + 13 : CC;
  float bs = 0.0f, f = 0.0f;
  for (int c = c0; c < c1; ++c) {
    const float wmv = Wm[c * DD + L];
    const float sf = (float)smask[b * CC + c];
    bs = fmaf(sf, wmv, bs);
    f += wmv;
  }
  red[w * 2][L] = bs;
  red[w * 2 + 1][L] = f;
  __syncthreads();
  if (w == 0) {
    bs = (red[0][L] + red[2][L]) + (red[4][L] + red[6][L]);
    f  = (red[1][L] + red[3][L]) + (red[5][L] + red[7][L]);
    ws[b * 128 + L] = bs;
    const float s1 = allsum64(f);
    const float s2 = allsum64(f * f);
    const float mu = s1 * (1.0f / 64.0f);
    const float vr = fmaf(-mu, mu, s2 * (1.0f / 64.0f));
    const float rs = rsqrtf(vr + LN_EPS);
    ws[b * 128 + 64 + L] = fmaf((f - mu) * rs, gamma[L], beta[L]);
  }
}

// ---- main: LDS-free MFMA, x loaded fully upfront, NT stores ----
__global__ __launch_bounds__(256, 2)
void ipmask_mfma3(const float* __restrict__ x, const float* __restrict__ W,
                  const float* __restrict__ gamma, const float* __restrict__ beta,
                  const int* __restrict__ tmask, const int* __restrict__ smask,
                  const float* __restrict__ ws, float* __restrict__ out) {
  const int t = threadIdx.x, L = t & 63;
  const int q = L >> 4, m16 = L & 15;
  const int gw = (blockIdx.x << 2) + (t >> 6);      // 4096 waves
  const int b = gw >> 6;
  const int rowBase = (b << 12) + ((gw & 63) << 6); // 64 rows per wave

  const int* smB = smask + b * CC;

  // ---- all x loads upfront, row-burst order: lines fetched exactly once ----
  float xf[4][4][4];   // [mt][ks][j]
#pragma unroll
  for (int mt = 0; mt < 4; ++mt) {
    const float* xr = x + (size_t)(rowBase + mt * 16 + m16) * CC;
#pragma unroll
    for (int ks = 0; ks < 4; ++ks) {
#pragma unroll
      for (int j = 0; j < 4; ++j) {
        const int c = ks * 16 + q * 4 + j;
        xf[mt][ks][j] = (c < CC) ? xr[c] : 0.0f;
      }
    }
  }
  const int tmv = tmask[rowBase + L];                // coalesced, 1 dword/lane

  // ---- acc init = bias ----
  f32x4 acc[4][4];
#pragma unroll
  for (int nt = 0; nt < 4; ++nt) {
    const float bias_nt = ws[b * 128 + nt * 16 + m16];
#pragma unroll
    for (int mt = 0; mt < 4; ++mt) {
      acc[mt][nt][0] = bias_nt; acc[mt][nt][1] = bias_nt;
      acc[mt][nt][2] = bias_nt; acc[mt][nt][3] = bias_nt;
    }
  }

#pragma unroll
  for (int ks = 0; ks < 4; ++ks) {
    // B frags rebuilt per ks (W is L1-hot: 13 KB)
    FragU bmu[4], bcu[4];
#pragma unroll
    for (int j = 0; j < 4; ++j) {
      const int c = ks * 16 + q * 4 + j;
      const int smv = (c < CC) ? smB[c] : 1;
#pragma unroll
      for (int nt = 0; nt < 4; ++nt) {
        const int n = nt * 16 + m16;
        float we = 0.0f;
        if (c < CC) we = W[c * DD + n];
        if (smv) we = 0.0f;
        const unsigned u = __float_as_uint(we);
        const unsigned h = u >> 16;
        const float hf = __uint_as_float(u & 0xFFFF0000u);
        const unsigned l = __float_as_uint(we - hf) >> 16;
        bmu[nt].i[j] = (int)(h | (h << 16));
        bcu[nt].i[j] = (int)l;
      }
    }
#pragma unroll
    for (int mt = 0; mt < 4; ++mt) {
      FragU au;
#pragma unroll
      for (int j = 0; j < 4; ++j) au.i[j] = pack_hl(xf[mt][ks][j]);
#pragma unroll
      for (int nt = 0; nt < 4; ++nt) {
        acc[mt][nt] = __builtin_amdgcn_mfma_f32_16x16x32_bf16(au.s, bmu[nt].s, acc[mt][nt], 0, 0, 0);
        acc[mt][nt] = __builtin_amdgcn_mfma_f32_16x16x32_bf16(au.s, bcu[nt].s, acc[mt][nt], 0, 0, 0);
      }
    }
  }

  // ---- epilogue: LN per row, tmask via shfl, NT stores ----
  float g_[4], b_[4], cons_[4];
#pragma unroll
  for (int nt = 0; nt < 4; ++nt) {
    g_[nt] = gamma[nt * 16 + m16];
    b_[nt] = beta[nt * 16 + m16];
    cons_[nt] = ws[b * 128 + 64 + nt * 16 + m16];
  }
#pragma unroll
  for (int mt = 0; mt < 4; ++mt) {
#pragma unroll
    for (int rg = 0; rg < 4; ++rg) {
      float su = 0.0f, sq = 0.0f;
#pragma unroll
      for (int nt = 0; nt < 4; ++nt) {
        const float v = acc[mt][nt][rg];
        su += v;
        sq = fmaf(v, v, sq);
      }
      su = allsum16(su);
      sq = allsum16(sq);
      const float mu = su * (1.0f / 64.0f);
      const float vr = fmaf(-mu, mu, sq * (1.0f / 64.0f));
      const float rs = rsqrtf(vr + LN_EPS);
      const int rloc = mt * 16 + q * 4 + rg;
      const int tm = __shfl(tmv, rloc, 64);
      const size_t obase = (size_t)(rowBase + rloc) * DD;
#pragma unroll
      for (int nt = 0; nt < 4; ++nt) {
        float val = fmaf((acc[mt][nt][rg] - mu) * rs, g_[nt], b_[nt]);
        if (tm) val = cons_[nt];
        __builtin_nontemporal_store(val, &out[obase + nt * 16 + m16]);
      }
    }
  }
}

extern "C" void kernel_launch(void* const* d_in, const int* in_sizes, int n_in,
                              void* d_out, int out_size, void* d_ws, size_t ws_size,
                              hipStream_t stream) {
  const float* x     = (const float*)d_in[0];
  const float* W     = (const float*)d_in[1];
  const float* Wm    = (const float*)d_in[2];
  const float* gamma = (const float*)d_in[3];
  const float* beta  = (const float*)d_in[4];
  const int*   tmask = (const int*)d_in[5];
  const int*   smask = (const int*)d_in[6];
  float* out = (float*)d_out;
  float* ws  = (float*)d_ws;

  ipmask_setup3<<<dim3(BB), dim3(256), 0, stream>>>(Wm, gamma, beta, smask, ws);
  ipmask_mfma3<<<dim3(1024), dim3(256), 0, stream>>>(
      x, W, gamma, beta, tmask, smask, ws, out);
}